// Round 2
// baseline (244.909 us; speedup 1.0000x reference)
//
#include <hip/hip_runtime.h>

// BioConvolution: 256 independent per-location GEMMs
//   C_l (64 x 128) = A_l (64 x 1024) * B_l (1024 x 128) + bias, ReLU
// f-split 4-way: block (l, fq) computes C_l[:, fq*32 : fq*32+32].
// Grid 1024 = 4 blocks/CU -> 16 waves/CU (vs 4 in R1).
// Swizzle: l = bx & 255, fq = bx >> 8 -> sibling blocks (same l) sit 256 apart
// = same XCD (256 % 8 == 0), sharing the X tile in that XCD's L2.

typedef __bf16 bf16x8 __attribute__((ext_vector_type(8)));
typedef float f32x4 __attribute__((ext_vector_type(4)));

#define SA 72   // A LDS row stride (ushort units): 144 B rows, 16B-aligned frags
#define SBQ 36  // B LDS k-pair row stride (uint units)

__device__ __forceinline__ unsigned pack2(float a, float b) {
  // native converts -> v_cvt_pk_bf16_f32 on gfx950
  __bf16 lo = (__bf16)a, hi = (__bf16)b;
  unsigned short ul = __builtin_bit_cast(unsigned short, lo);
  unsigned short uh = __builtin_bit_cast(unsigned short, hi);
  return (unsigned)ul | ((unsigned)uh << 16);
}

__global__ __launch_bounds__(256) void bioconv_mfma(
    const float* __restrict__ X, const float* __restrict__ Fw,
    const float* __restrict__ bias, float* __restrict__ out) {
  const int bx = blockIdx.x;
  const int l = bx & 255;      // location
  const int fq = bx >> 8;      // f quarter: cols [fq*32, fq*32+32)
  const int r = l >> 4;
  const int c = l & 15;
  const int t = threadIdx.x;
  const int w = t >> 6;        // wave 0..3 -> rows [w*16, w*16+16)
  const int lane = t & 63;
  const int q = lane >> 4;     // quad 0..3
  const int nl = lane & 15;

  __shared__ __align__(16) unsigned short As[2][64 * SA];  // 2 x 9216 B
  __shared__ __align__(16) unsigned Bs[2][32 * SBQ];       // 2 x 4608 B (k-pair packed)

  const float* Fl = Fw + (size_t)l * 131072 + fq * 32;

  f32x4 acc[2];
  acc[0] = (f32x4){0.f, 0.f, 0.f, 0.f};
  acc[1] = (f32x4){0.f, 0.f, 0.f, 0.f};

  float4 areg[4], b0reg, b1reg;

  // staging split (thread-constant)
  const int a_n0 = t >> 4;          // A: 16 threads cover one 256 B row segment
  const int a_f4 = t & 15;
  const int b_kp = t >> 3;          // B: 8 threads cover one 128 B k-row chunk
  const int b_fo = (t & 7) << 2;

  const float* xrowbase = X + c * 256 + a_f4 * 4;

  auto issue_loads = [&](int s) {
    const int i = s >> 2;
    const int koff = (s & 3) << 6;
    const float* xb = xrowbase + (r * 4 + i) * 4096 + koff;
#pragma unroll
    for (int rep = 0; rep < 4; ++rep) {
      const int n = a_n0 + (rep << 4);
      areg[rep] = *(const float4*)(xb + (size_t)n * 262144);
    }
    const float* g = Fl + s * 8192 + b_kp * 256 + b_fo;
    b0reg = *(const float4*)(g);        // k = s*64 + 2*kp
    b1reg = *(const float4*)(g + 128);  // k = s*64 + 2*kp + 1
  };

  auto store_lds = [&](int buf) {
#pragma unroll
    for (int rep = 0; rep < 4; ++rep) {
      const int n = a_n0 + (rep << 4);
      uint2 v;
      v.x = pack2(areg[rep].x, areg[rep].y);
      v.y = pack2(areg[rep].z, areg[rep].w);
      *(uint2*)&As[buf][n * SA + a_f4 * 4] = v;
    }
    uint4 v;  // word j = bf16 B[2kp][f+j] | (bf16 B[2kp+1][f+j] << 16)
    v.x = pack2(b0reg.x, b1reg.x);
    v.y = pack2(b0reg.y, b1reg.y);
    v.z = pack2(b0reg.z, b1reg.z);
    v.w = pack2(b0reg.w, b1reg.w);
    *(uint4*)&Bs[buf][b_kp * SBQ + b_fo] = v;
  };

  issue_loads(0);
  store_lds(0);

  for (int s = 0; s < 16; ++s) {
    __syncthreads();
    if (s < 15) issue_loads(s + 1);  // overlap with compute below
    const int buf = s & 1;
#pragma unroll
    for (int kc = 0; kc < 2; ++kc) {
      // A fragment: rows w*16 + nl, k = kc*32 + q*8 + j
      bf16x8 af = *(const bf16x8*)&As[buf][(w * 16 + nl) * SA + kc * 32 + q * 8];
#pragma unroll
      for (int fb = 0; fb < 2; ++fb) {
        // B fragment: k = kc*32 + q*8 + j, col = fb*16 + nl
        const unsigned* bp = &Bs[buf][(kc * 16 + q * 4) * SBQ + fb * 16 + nl];
        uint4 v;
        v.x = bp[0];
        v.y = bp[SBQ];
        v.z = bp[2 * SBQ];
        v.w = bp[3 * SBQ];
        bf16x8 bfr = __builtin_bit_cast(bf16x8, v);
        acc[fb] = __builtin_amdgcn_mfma_f32_16x16x32_bf16(af, bfr, acc[fb], 0, 0, 0);
      }
    }
    if (s < 15) store_lds((s + 1) & 1);
  }

  // epilogue: bias + ReLU; D layout: row = q*4 + reg, col = nl
#pragma unroll
  for (int fb = 0; fb < 2; ++fb) {
    const int f = fq * 32 + fb * 16 + nl;
    const float bv = bias[f];
    float* ob = out + (size_t)l * 128 + f;
#pragma unroll
    for (int v = 0; v < 4; ++v) {
      const int n = w * 16 + q * 4 + v;
      const float val = acc[fb][v] + bv;
      ob[(size_t)n * 32768] = fmaxf(val, 0.f);
    }
  }
}

extern "C" void kernel_launch(void* const* d_in, const int* in_sizes, int n_in,
                              void* d_out, int out_size, void* d_ws, size_t ws_size,
                              hipStream_t stream) {
  const float* X = (const float*)d_in[0];
  const float* Fw = (const float*)d_in[1];
  const float* bias = (const float*)d_in[2];
  float* out = (float*)d_out;
  bioconv_mfma<<<1024, 256, 0, stream>>>(X, Fw, bias, out);
}

// Round 4
// 240.092 us; speedup vs baseline: 1.0201x; 1.0201x over previous
//
#include <hip/hip_runtime.h>

// BioConvolution: 256 per-location GEMMs, C_l(64x128) = A_l(64x1024)*B_l(1024x128)+bias, ReLU
// X layout [n][h][w][ch] strides: n=262144, h=4096, w=64, ch=1.
// A_l[n][k] = X[n, r*4+i, c*4+j, ch], k = i*256 + j*64 + ch
//   -> offset = n*262144 + r*16384 + i*4096 + c*256 + j*64 + ch   (R3 bug: had c*1024, j*256)
// B_l[k][f] = Fw[l*131072 + k*128 + f]
//
// R4: barrier-free wave-autonomous pipeline (R3 design, indexing fixed).
// 1 wave / workgroup, tile 64x32. grid 1024: l = bx&255, fq = bx>>8.
// A: global->register direct (8 k-consecutive floats are contiguous in X).
// B: global->reg->pack bf16 pairs->wave-private LDS (transpose), NO __syncthreads:
// all ordering is wave-internal s_waitcnt; prefetch (A depth-2, B depth-3) stays in flight.

typedef __bf16 bf16x8 __attribute__((ext_vector_type(8)));
typedef float f32x4 __attribute__((ext_vector_type(4)));

#define SBQ 36  // LDS B row stride in words (16 kp-rows per stage, +4 pad)

__device__ __forceinline__ unsigned pack2(float a, float b) {
  __bf16 lo = (__bf16)a, hi = (__bf16)b;
  return (unsigned)__builtin_bit_cast(unsigned short, lo) |
         ((unsigned)__builtin_bit_cast(unsigned short, hi) << 16);
}
__device__ __forceinline__ bf16x8 cvt8(float4 lo, float4 hi) {
  uint4 v;
  v.x = pack2(lo.x, lo.y);
  v.y = pack2(lo.z, lo.w);
  v.z = pack2(hi.x, hi.y);
  v.w = pack2(hi.z, hi.w);
  return __builtin_bit_cast(bf16x8, v);
}

__global__ __launch_bounds__(64) void bioconv_wave(
    const float* __restrict__ X, const float* __restrict__ Fw,
    const float* __restrict__ bias, float* __restrict__ out) {
  const int bx = blockIdx.x;
  const int l = bx & 255;   // location
  const int fq = bx >> 8;   // f quarter
  const int r = l >> 4, c = l & 15;
  const int lane = threadIdx.x;  // 0..63 (one wave)
  const int q = lane >> 4, nl = lane & 15;

  __shared__ __align__(16) unsigned Bs[2][16 * SBQ];  // 4.6 KB, wave-private

  // A row bases: row n = mb*16+nl; q*8 = k sub-offset within a 32-ch half-run
  const float* pA[4];
#pragma unroll
  for (int mb = 0; mb < 4; ++mb)
    pA[mb] = X + (size_t)(mb * 16 + nl) * 262144 + r * 16384 + c * 256 + q * 8;

  // B: kp0 = lane>>3 (0..7), col chunk (lane&7)*4 within the 32-col slice
  const float* pB = Fw + (size_t)l * 131072 + fq * 32 + (lane >> 3) * 256 + (lane & 7) * 4;
  unsigned* const wpB = (unsigned*)Bs + ((lane >> 3) * SBQ + (lane & 7) * 4);

  float4 aR[2][8];   // A prefetch ring, depth 2 (1 step = 8 float4/lane)
  float4 bR[3][4];   // B prefetch ring, depth 3 (1 step = 4 float4/lane)
  f32x4 acc[4][2];
#pragma unroll
  for (int mb = 0; mb < 4; ++mb) {
    acc[mb][0] = (f32x4){0.f, 0.f, 0.f, 0.f};
    acc[mb][1] = (f32x4){0.f, 0.f, 0.f, 0.f};
  }

  auto issueA = [&](int s, int ring) {
    const int p = s >> 1;  // pixel index 0..15: i = p>>2, j = p&3
    const int off = (p >> 2) * 4096 + (p & 3) * 64 + (s & 1) * 32;
#pragma unroll
    for (int mb = 0; mb < 4; ++mb) {
      aR[ring][mb * 2] = *(const float4*)(pA[mb] + off);
      aR[ring][mb * 2 + 1] = *(const float4*)(pA[mb] + off + 4);
    }
  };
  auto issueB = [&](int s, int ring) {
#pragma unroll
    for (int rep = 0; rep < 2; ++rep) {
      const float* g = pB + s * 4096 + rep * 2048;
      bR[ring][rep * 2] = *(const float4*)(g);            // k = s*32 + 2*kp
      bR[ring][rep * 2 + 1] = *(const float4*)(g + 128);  // k odd
    }
  };
  auto writeB = [&](int s, int ring) {
    unsigned* wp = wpB + (s & 1) * (16 * SBQ);
#pragma unroll
    for (int rep = 0; rep < 2; ++rep) {
      float4 e0 = bR[ring][rep * 2], e1 = bR[ring][rep * 2 + 1];
      uint4 v;  // word = bf16 B[2kp][col] | bf16 B[2kp+1][col] << 16
      v.x = pack2(e0.x, e1.x);
      v.y = pack2(e0.y, e1.y);
      v.z = pack2(e0.z, e1.z);
      v.w = pack2(e0.w, e1.w);
      *(uint4*)(wp + rep * 8 * SBQ) = v;
    }
  };

  // ---- pipeline preamble ----
  issueA(0, 0);
  issueB(0, 0);
  issueA(1, 1);
  issueB(1, 1);
  issueB(2, 2);
  writeB(0, 0);  // waits bR[0]; fills LDS buf 0

  // ---- 32 fully-unrolled K-steps (BK=32), no barriers ----
#pragma unroll
  for (int s = 0; s < 32; ++s) {
    if (s + 3 < 32) issueB(s + 3, (s + 3) % 3);
    if (s + 1 < 32) writeB(s + 1, (s + 1) % 3);  // -> buf[(s+1)&1]; reads of buf[s&1] unaffected

    bf16x8 af[4];
#pragma unroll
    for (int mb = 0; mb < 4; ++mb)
      af[mb] = cvt8(aR[s & 1][mb * 2], aR[s & 1][mb * 2 + 1]);  // waits aR[s&1]
    if (s + 2 < 32) issueA(s + 2, s & 1);

#pragma unroll
    for (int fb = 0; fb < 2; ++fb) {
      const unsigned* bp = &Bs[s & 1][(q * 4) * SBQ + fb * 16 + nl];
      uint4 v;
      v.x = bp[0];
      v.y = bp[SBQ];
      v.z = bp[2 * SBQ];
      v.w = bp[3 * SBQ];
      bf16x8 bfr = __builtin_bit_cast(bf16x8, v);
#pragma unroll
      for (int mb = 0; mb < 4; ++mb)
        acc[mb][fb] = __builtin_amdgcn_mfma_f32_16x16x32_bf16(af[mb], bfr, acc[mb][fb], 0, 0, 0);
    }
  }

  // ---- epilogue: bias + ReLU; D layout row = q*4+reg, col = nl ----
#pragma unroll
  for (int fb = 0; fb < 2; ++fb) {
    const int f = fq * 32 + fb * 16 + nl;
    const float bv = bias[f];
    float* ob = out + (size_t)l * 128 + f;
#pragma unroll
    for (int mb = 0; mb < 4; ++mb) {
#pragma unroll
      for (int v = 0; v < 4; ++v) {
        const int row = mb * 16 + q * 4 + v;
        ob[(size_t)row * 32768] = fmaxf(acc[mb][fb][v] + bv, 0.f);
      }
    }
  }
}

extern "C" void kernel_launch(void* const* d_in, const int* in_sizes, int n_in,
                              void* d_out, int out_size, void* d_ws, size_t ws_size,
                              hipStream_t stream) {
  const float* X = (const float*)d_in[0];
  const float* Fw = (const float*)d_in[1];
  const float* bias = (const float*)d_in[2];
  float* out = (float*)d_out;
  bioconv_wave<<<1024, 64, 0, stream>>>(X, Fw, bias, out);
}